// Round 1
// baseline (628.682 us; speedup 1.0000x reference)
//
#include <hip/hip_runtime.h>
#include <hip/hip_bf16.h>

// Fused additive-attention (Bahdanau-style) on MI355X.
//   att1 = enc @ W_enc + b_enc            [B,L,A]  (bf16 MFMA, fp32 accum)
//   att2 = dh @ W_dec + b_dec             [B,A]
//   s    = tanh(att1+att2) . W_full       [B,L]    (b_full dropped: softmax-invariant)
//   alpha= softmax_L(s); awe = sum_l alpha * att1  [B,A]
// Two-level (flash-style) softmax: each (b, l-tile of 64) wg emits
// (m_tile, sum_tile, pawe[512]) so att1 is never materialized in HBM.
//
// B=64, L=1024, E=2048, A=512.
// ws layout: Wt bf16 [512][2048] (2MB) | att2 f32 (128KB) | pawe f32 1024*512 (2MB) | ms f32 1024*2 (8KB)
// total ws ~4.34 MB.

#define Bn 64
#define Ln 1024
#define En 2048
#define An 512
#define TM 64          // l-rows per workgroup
#define NTILES (Ln/TM) // 16
#define AWE_OFF 0
#define ALPHA_OFF (Bn*An) // 32768

using short8 = __attribute__((ext_vector_type(8))) short;
using f32x4  = __attribute__((ext_vector_type(4))) float;

__device__ inline short f2bf(float x){
    unsigned u = __builtin_bit_cast(unsigned, x);
    unsigned r = (u + 0x7fffu + ((u >> 16) & 1u)) >> 16;
    return (short)r;
}

// ---------- kernel 0a: Wt[a][e] = bf16(W_enc[e][a]) ----------
__global__ __launch_bounds__(256) void k_trans(const float* __restrict__ W,
                                               unsigned short* __restrict__ Wt){
    __shared__ float t[32][33];
    int e0 = blockIdx.x * 32, a0 = blockIdx.y * 32;
    int tid = threadIdx.x;
    int c = tid & 31, r8 = tid >> 5;      // 8 rows per pass
#pragma unroll
    for (int i = 0; i < 4; ++i){
        int r = r8 + i * 8;
        t[r][c] = W[(size_t)(e0 + r) * An + a0 + c];
    }
    __syncthreads();
#pragma unroll
    for (int i = 0; i < 4; ++i){
        int ar = r8 + i * 8;              // a-local index
        Wt[(size_t)(a0 + ar) * En + e0 + c] = (unsigned short)f2bf(t[c][ar]);
    }
}

// ---------- kernel 0b: att2[b][a] = dh[b] @ W_dec[:,a] + b_dec[a] ----------
__global__ __launch_bounds__(256) void k_att2(const float* __restrict__ dh,
                                              const float* __restrict__ Wd,
                                              const float* __restrict__ bd,
                                              float* __restrict__ att2){
    int b = blockIdx.x, tid = threadIdx.x;
    __shared__ float dl[512];
    dl[tid]       = dh[b * 512 + tid];
    dl[tid + 256] = dh[b * 512 + tid + 256];
    __syncthreads();
    for (int a = tid; a < An; a += 256){
        float s = bd[a];
        for (int k = 0; k < 512; ++k)
            s = fmaf(dl[k], Wd[(size_t)k * An + a], s);
        att2[b * An + a] = s;
    }
}

// ---------- kernel 1: fused GEMM + score + tile-softmax + partial awe ----------
__global__ __launch_bounds__(512, 2)
void k_main(const float* __restrict__ enc, const unsigned short* __restrict__ Wt,
            const float* __restrict__ benc, const float* __restrict__ att2,
            const float* __restrict__ wfull, float* __restrict__ out,
            float* __restrict__ pawe_ws, float* __restrict__ ms_ws){
    int wg   = blockIdx.x;            // 0..1023
    int b    = wg >> 4;
    int tile = wg & 15;
    int l0   = tile * TM;
    int tid  = threadIdx.x;
    int lane = tid & 63, w = tid >> 6;
    int wm = w >> 2, wn = w & 3;      // wave: rows wm*32..+32, cols wn*128..+128

    __shared__ unsigned short Alds[TM * 64];   // 8 KB, XOR-swizzled
    __shared__ float red[4][TM];
    __shared__ float plds[TM];
    __shared__ float pawe_lds[2][512];
    char* alds = (char*)Alds;

    const float* Ag = enc + ((size_t)(b * Ln + l0)) * En;

    f32x4 acc[2][8];
#pragma unroll
    for (int mi = 0; mi < 2; ++mi)
#pragma unroll
        for (int ni = 0; ni < 8; ++ni)
            acc[mi][ni] = (f32x4){0.f, 0.f, 0.f, 0.f};

    // staging: thread t loads 8 fp32 of row srow at k-offset sc8
    int srow  = tid >> 3;
    int sc8   = (tid & 7) * 8;
    int sbyte = srow * 128 + ((sc8 * 2) ^ ((srow & 7) << 4));

    // fragment addressing
    int arow = wm * 32 + (lane & 15);     // +mi*16
    int akb  = (lane >> 4) * 16;          // byte offset of lane's k-group
    const unsigned short* Bbase = Wt + (size_t)(wn * 128 + (lane & 15)) * En + (lane >> 4) * 8;

    const float* ap = Ag + (size_t)srow * En + sc8;
    float4 r0 = *(const float4*)(ap);
    float4 r1 = *(const float4*)(ap + 4);

    for (int kt = 0; kt < En / 64; ++kt){
        __syncthreads();   // prev iter's LDS reads done
        short8 v;
        v[0] = f2bf(r0.x); v[1] = f2bf(r0.y); v[2] = f2bf(r0.z); v[3] = f2bf(r0.w);
        v[4] = f2bf(r1.x); v[5] = f2bf(r1.y); v[6] = f2bf(r1.z); v[7] = f2bf(r1.w);
        *(short8*)(alds + sbyte) = v;
        __syncthreads();
        if (kt < En / 64 - 1){
            const float* np = ap + (kt + 1) * 64;
            r0 = *(const float4*)(np);
            r1 = *(const float4*)(np + 4);
        }
        const unsigned short* bk = Bbase + kt * 64;
#pragma unroll
        for (int s = 0; s < 2; ++s){
            short8 af[2];
#pragma unroll
            for (int mi = 0; mi < 2; ++mi){
                int ar = arow + mi * 16;
                int kb = s * 64 + akb;
                af[mi] = *(short8*)(alds + ar * 128 + (kb ^ ((ar & 7) << 4)));
            }
#pragma unroll
            for (int ni = 0; ni < 8; ++ni){
                short8 bf = *(const short8*)(bk + ni * 16 * En + s * 32);
                acc[0][ni] = __builtin_amdgcn_mfma_f32_16x16x32_bf16(af[0], bf, acc[0][ni], 0, 0, 0);
                acc[1][ni] = __builtin_amdgcn_mfma_f32_16x16x32_bf16(af[1], bf, acc[1][ni], 0, 0, 0);
            }
        }
    }

    // ---- epilogue ----
    // per-lane column params (8 cols: ni*16 + lane&15 within wave's 128-col slice)
    float be[8], a2[8], wf[8];
    int cbase = wn * 128 + (lane & 15);
    const float* att2b = att2 + b * An;
#pragma unroll
    for (int ni = 0; ni < 8; ++ni){
        int c = cbase + ni * 16;
        be[ni] = benc[c];
        a2[ni] = att2b[c];
        wf[ni] = wfull[c];
    }

    // v = att1 (incl. b_enc); score partial per owned row
    float tsum[2][4];
#pragma unroll
    for (int mi = 0; mi < 2; ++mi)
#pragma unroll
        for (int j = 0; j < 4; ++j)
            tsum[mi][j] = 0.f;
#pragma unroll
    for (int mi = 0; mi < 2; ++mi)
#pragma unroll
        for (int ni = 0; ni < 8; ++ni)
#pragma unroll
            for (int j = 0; j < 4; ++j){
                float vv = acc[mi][ni][j] + be[ni];
                acc[mi][ni][j] = vv;
                tsum[mi][j] += tanhf(vv + a2[ni]) * wf[ni];
            }

    // reduce across the 16 lanes of each row-group
#pragma unroll
    for (int mi = 0; mi < 2; ++mi)
#pragma unroll
        for (int j = 0; j < 4; ++j){
            float t = tsum[mi][j];
            t += __shfl_xor(t, 1); t += __shfl_xor(t, 2);
            t += __shfl_xor(t, 4); t += __shfl_xor(t, 8);
            if ((lane & 15) == 0)
                red[wn][wm * 32 + mi * 16 + (lane >> 4) * 4 + j] = t;
        }
    __syncthreads();

    if (tid < TM)
        plds[tid] = red[0][tid] + red[1][tid] + red[2][tid] + red[3][tid];
    __syncthreads();

    if (tid < 64){   // wave 0: tile softmax stats
        float s = plds[lane];
        out[ALPHA_OFF + b * Ln + l0 + lane] = s;   // raw score, finalized in k_final
        float m = s;
        m = fmaxf(m, __shfl_xor(m, 1));  m = fmaxf(m, __shfl_xor(m, 2));
        m = fmaxf(m, __shfl_xor(m, 4));  m = fmaxf(m, __shfl_xor(m, 8));
        m = fmaxf(m, __shfl_xor(m, 16)); m = fmaxf(m, __shfl_xor(m, 32));
        float p = __expf(s - m);
        float sm = p;
        sm += __shfl_xor(sm, 1);  sm += __shfl_xor(sm, 2);
        sm += __shfl_xor(sm, 4);  sm += __shfl_xor(sm, 8);
        sm += __shfl_xor(sm, 16); sm += __shfl_xor(sm, 32);
        plds[lane] = p;
        if (lane == 0){ ms_ws[wg * 2] = m; ms_ws[wg * 2 + 1] = sm; }
    }
    __syncthreads();

    // partial awe: pp[ni] = sum over owned rows of p[row]*att1
    float pp[8];
#pragma unroll
    for (int ni = 0; ni < 8; ++ni) pp[ni] = 0.f;
#pragma unroll
    for (int mi = 0; mi < 2; ++mi)
#pragma unroll
        for (int j = 0; j < 4; ++j){
            float pr = plds[wm * 32 + mi * 16 + (lane >> 4) * 4 + j];
#pragma unroll
            for (int ni = 0; ni < 8; ++ni)
                pp[ni] += pr * acc[mi][ni][j];
        }
#pragma unroll
    for (int ni = 0; ni < 8; ++ni){
        pp[ni] += __shfl_xor(pp[ni], 16);
        pp[ni] += __shfl_xor(pp[ni], 32);
    }
    if (lane < 16){
#pragma unroll
        for (int ni = 0; ni < 8; ++ni)
            pawe_lds[wm][wn * 128 + ni * 16 + lane] = pp[ni];
    }
    __syncthreads();
    pawe_ws[(size_t)wg * An + tid] = pawe_lds[0][tid] + pawe_lds[1][tid];
}

// ---------- kernel 2: combine tiles, finalize awe + alpha ----------
__global__ __launch_bounds__(256) void k_final(const float* __restrict__ pawe,
                                               const float* __restrict__ ms,
                                               float* __restrict__ out){
    int b = blockIdx.x, tid = threadIdx.x;
    __shared__ float scale[NTILES];
    __shared__ float sh[2];   // inv_total, global max
    if (tid < 64){
        int lane = tid;
        float m = -1e30f, su = 0.f;
        if (lane < NTILES){ m = ms[(b * NTILES + lane) * 2]; su = ms[(b * NTILES + lane) * 2 + 1]; }
        float mm = m;
        mm = fmaxf(mm, __shfl_xor(mm, 1)); mm = fmaxf(mm, __shfl_xor(mm, 2));
        mm = fmaxf(mm, __shfl_xor(mm, 4)); mm = fmaxf(mm, __shfl_xor(mm, 8));
        float sc = (lane < NTILES) ? su * __expf(m - mm) : 0.f;
        float tot = sc;
        tot += __shfl_xor(tot, 1); tot += __shfl_xor(tot, 2);
        tot += __shfl_xor(tot, 4); tot += __shfl_xor(tot, 8);
        if (lane < NTILES) scale[lane] = __expf(m - mm);
        if (lane == 0){ sh[0] = 1.0f / tot; sh[1] = mm; }
    }
    __syncthreads();
    float inv = sh[0], mm = sh[1];
    for (int a = tid; a < An; a += 256){
        float s = 0.f;
#pragma unroll
        for (int t = 0; t < NTILES; ++t)
            s += pawe[((size_t)(b * NTILES + t)) * An + a] * scale[t];
        out[AWE_OFF + b * An + a] = s * inv;
    }
    for (int l = tid; l < Ln; l += 256){
        float s = out[ALPHA_OFF + b * Ln + l];
        out[ALPHA_OFF + b * Ln + l] = __expf(s - mm) * inv;
    }
}

extern "C" void kernel_launch(void* const* d_in, const int* in_sizes, int n_in,
                              void* d_out, int out_size, void* d_ws, size_t ws_size,
                              hipStream_t stream){
    const float* enc   = (const float*)d_in[0];
    const float* dh    = (const float*)d_in[1];
    const float* Wenc  = (const float*)d_in[2];
    const float* benc  = (const float*)d_in[3];
    const float* Wdec  = (const float*)d_in[4];
    const float* bdec  = (const float*)d_in[5];
    const float* wfull = (const float*)d_in[6];
    // d_in[7] = b_full: softmax-invariant, unused.
    float* out = (float*)d_out;

    char* ws = (char*)d_ws;
    unsigned short* Wt = (unsigned short*)ws;                       // 2 MB
    float* att2 = (float*)(ws + (2u << 20));                        // 128 KB
    float* pawe = (float*)(ws + (2u << 20) + (128u << 10));         // 2 MB
    float* msb  = (float*)(ws + (4u << 20) + (128u << 10));         // 8 KB
    // total ws use ~4.34 MB

    k_trans<<<dim3(En / 32, An / 32), 256, 0, stream>>>(Wenc, Wt);
    k_att2<<<Bn, 256, 0, stream>>>(dh, Wdec, bdec, att2);
    k_main<<<Bn * NTILES, 512, 0, stream>>>(enc, Wt, benc, att2, wfull, out, pawe, msb);
    k_final<<<Bn, 256, 0, stream>>>(pawe, msb, out);
}

// Round 2
// 483.339 us; speedup vs baseline: 1.3007x; 1.3007x over previous
//
#include <hip/hip_runtime.h>
#include <hip/hip_bf16.h>

// Fused additive-attention (Bahdanau-style) on MI355X.
//   att1 = enc @ W_enc + b_enc            [B,L,A]  (bf16 MFMA, fp32 accum)
//   att2 = dh @ W_dec + b_dec             [B,A]
//   s    = tanh(att1+att2) . W_full       [B,L]    (b_full dropped: softmax-invariant)
//   alpha= softmax_L(s); awe = sum_l alpha * att1  [B,A]
// Flash-style two-level softmax: each (b, l-tile of 64) wg emits
// (m_tile, sum_tile, pawe[512]); att1 never hits HBM.
//
// R2 changes vs R1 (which was latency-bound at 645us, MfmaUtil 8.6%):
//  - W pre-packed into MFMA B-fragment order (k_pack): wave B-load = 1KB
//    contiguous instead of 16 scattered 64B lines (16x fewer L2 transactions).
//  - k_main: single barrier per 64-wide K-step via double-buffered A-LDS,
//    2 A-tiles in flight in registers, loop unrolled x2 (static reg indices).

#define Bn 64
#define Ln 1024
#define En 2048
#define An 512
#define TM 64          // l-rows per workgroup
#define NTILES (Ln/TM) // 16
#define AWE_OFF 0
#define ALPHA_OFF (Bn*An) // 32768

using short8 = __attribute__((ext_vector_type(8))) short;
using f32x4  = __attribute__((ext_vector_type(4))) float;

__device__ inline short f2bf(float x){
    unsigned u = __builtin_bit_cast(unsigned, x);
    unsigned r = (u + 0x7fffu + ((u >> 16) & 1u)) >> 16;
    return (short)r;
}

// ---------- kernel 0a: pack W_enc into MFMA B-fragment layout ----------
// frag f = kb*32 + nc  (kb: k-block of 32, nc: col-block of 16)
// Wp[f*512 + lane*8 + j] = bf16(W[kb*32 + (lane>>4)*8 + j][nc*16 + (lane&15)])
// A wave's B-fragment load is then 64 lanes x 16B = 1KB contiguous.
__global__ __launch_bounds__(256) void k_pack(const float* __restrict__ W,
                                              unsigned short* __restrict__ Wp){
    int t = blockIdx.x * 256 + threadIdx.x;   // 512 wgs * 256 = 131072 = 2048 frags * 64 lanes
    int f = t >> 6, lane = t & 63;
    int kb = f >> 5, nc = f & 31;
    int k0 = kb * 32 + (lane >> 4) * 8;
    int col = nc * 16 + (lane & 15);
    short8 v;
#pragma unroll
    for (int j = 0; j < 8; ++j)
        v[j] = f2bf(W[(size_t)(k0 + j) * An + col]);
    *(short8*)(Wp + (size_t)f * 512 + lane * 8) = v;
}

// ---------- kernel 0b: att2[b][a] = dh[b] @ W_dec[:,a] + b_dec[a] ----------
__global__ __launch_bounds__(256) void k_att2(const float* __restrict__ dh,
                                              const float* __restrict__ Wd,
                                              const float* __restrict__ bd,
                                              float* __restrict__ att2){
    int b = blockIdx.x, tid = threadIdx.x;
    __shared__ float dl[512];
    dl[tid]       = dh[b * 512 + tid];
    dl[tid + 256] = dh[b * 512 + tid + 256];
    __syncthreads();
    for (int a = tid; a < An; a += 256){
        float s = bd[a];
        for (int k = 0; k < 512; ++k)
            s = fmaf(dl[k], Wd[(size_t)k * An + a], s);
        att2[b * An + a] = s;
    }
}

// ---------- kernel 1: fused GEMM + score + tile-softmax + partial awe ----------
__device__ inline void stage_tile(char* dst, int sbyte, float4 r0, float4 r1){
    short8 v;
    v[0] = f2bf(r0.x); v[1] = f2bf(r0.y); v[2] = f2bf(r0.z); v[3] = f2bf(r0.w);
    v[4] = f2bf(r1.x); v[5] = f2bf(r1.y); v[6] = f2bf(r1.z); v[7] = f2bf(r1.w);
    *(short8*)(dst + sbyte) = v;
}

__device__ inline void compute_tile(const char* abase, const unsigned short* Bw,
                                    int tile, int arow, int akb, f32x4 (&acc)[2][8]){
#pragma unroll
    for (int s = 0; s < 2; ++s){
        int kb = s * 64 + akb;
        int ar0 = arow, ar1 = arow + 16;
        short8 af0 = *(const short8*)(abase + ar0 * 128 + (kb ^ ((ar0 & 7) << 4)));
        short8 af1 = *(const short8*)(abase + ar1 * 128 + (kb ^ ((ar1 & 7) << 4)));
        const unsigned short* bk = Bw + ((size_t)(tile * 2 + s) * 32) * 512;
#pragma unroll
        for (int ni = 0; ni < 8; ++ni){
            short8 bf = *(const short8*)(bk + ni * 512);
            acc[0][ni] = __builtin_amdgcn_mfma_f32_16x16x32_bf16(af0, bf, acc[0][ni], 0, 0, 0);
            acc[1][ni] = __builtin_amdgcn_mfma_f32_16x16x32_bf16(af1, bf, acc[1][ni], 0, 0, 0);
        }
    }
}

__global__ __launch_bounds__(512)
void k_main(const float* __restrict__ enc, const unsigned short* __restrict__ Wp,
            const float* __restrict__ benc, const float* __restrict__ att2,
            const float* __restrict__ wfull, float* __restrict__ out,
            float* __restrict__ pawe_ws, float* __restrict__ ms_ws){
    int wg   = blockIdx.x;            // 0..1023
    int b    = wg >> 4;
    int tile = wg & 15;
    int l0   = tile * TM;
    int tid  = threadIdx.x;
    int lane = tid & 63, w = tid >> 6;
    int wm = w >> 2, wn = w & 3;      // wave: rows wm*32..+32, cols wn*128..+128

    __shared__ unsigned short Alds[2][TM * 64];   // 2 x 8 KB, XOR-swizzled
    __shared__ float red[4][TM];
    __shared__ float plds[TM];
    __shared__ float pawe_lds[2][512];
    char* alds0 = (char*)Alds[0];
    char* alds1 = (char*)Alds[1];

    f32x4 acc[2][8];
#pragma unroll
    for (int mi = 0; mi < 2; ++mi)
#pragma unroll
        for (int ni = 0; ni < 8; ++ni)
            acc[mi][ni] = (f32x4){0.f, 0.f, 0.f, 0.f};

    // staging: thread t loads 8 fp32 of row srow at 16B-chunk (tid&7), XOR-swizzled
    int srow  = tid >> 3;
    int sbyte = srow * 128 + (((tid & 7) * 16) ^ ((srow & 7) << 4));

    // fragment addressing
    int arow = wm * 32 + (lane & 15);     // +mi*16
    int akb  = (lane >> 4) * 16;          // byte offset of lane's k-group
    const unsigned short* Bw = Wp + (size_t)(wn * 8) * 512 + lane * 8;

    const float* ap = enc + ((size_t)(b * Ln + l0)) * En + (size_t)srow * En + (tid & 7) * 8;

    // prologue: tile0 -> LDS[0]; tile1 -> regs
    float4 a0 = *(const float4*)(ap),      a1 = *(const float4*)(ap + 4);
    stage_tile(alds0, sbyte, a0, a1);
    float4 b0 = *(const float4*)(ap + 64), b1 = *(const float4*)(ap + 68);

    for (int kt = 0; kt < En / 64; kt += 2){
        __syncthreads();
        // even phase: prefetch tile kt+2, stage tile kt+1 -> LDS[1], compute tile kt from LDS[0]
        if (kt + 2 < 32){
            a0 = *(const float4*)(ap + (kt + 2) * 64);
            a1 = *(const float4*)(ap + (kt + 2) * 64 + 4);
        }
        stage_tile(alds1, sbyte, b0, b1);
        compute_tile(alds0, Bw, kt, arow, akb, acc);
        __syncthreads();
        // odd phase: prefetch tile kt+3, stage tile kt+2 -> LDS[0], compute tile kt+1 from LDS[1]
        if (kt + 3 < 32){
            b0 = *(const float4*)(ap + (kt + 3) * 64);
            b1 = *(const float4*)(ap + (kt + 3) * 64 + 4);
        }
        if (kt + 2 < 32)
            stage_tile(alds0, sbyte, a0, a1);
        compute_tile(alds1, Bw, kt + 1, arow, akb, acc);
    }

    // ---- epilogue ----
    float be[8], a2[8], wf[8];
    int cbase = wn * 128 + (lane & 15);
    const float* att2b = att2 + b * An;
#pragma unroll
    for (int ni = 0; ni < 8; ++ni){
        int c = cbase + ni * 16;
        be[ni] = benc[c];
        a2[ni] = att2b[c];
        wf[ni] = wfull[c];
    }

    float tsum[2][4];
#pragma unroll
    for (int mi = 0; mi < 2; ++mi)
#pragma unroll
        for (int j = 0; j < 4; ++j)
            tsum[mi][j] = 0.f;
#pragma unroll
    for (int mi = 0; mi < 2; ++mi)
#pragma unroll
        for (int ni = 0; ni < 8; ++ni)
#pragma unroll
            for (int j = 0; j < 4; ++j){
                float vv = acc[mi][ni][j] + be[ni];
                acc[mi][ni][j] = vv;
                tsum[mi][j] += tanhf(vv + a2[ni]) * wf[ni];
            }

    // reduce across the 16 lanes of each row-group
#pragma unroll
    for (int mi = 0; mi < 2; ++mi)
#pragma unroll
        for (int j = 0; j < 4; ++j){
            float t = tsum[mi][j];
            t += __shfl_xor(t, 1); t += __shfl_xor(t, 2);
            t += __shfl_xor(t, 4); t += __shfl_xor(t, 8);
            if ((lane & 15) == 0)
                red[wn][wm * 32 + mi * 16 + (lane >> 4) * 4 + j] = t;
        }
    __syncthreads();

    if (tid < TM)
        plds[tid] = red[0][tid] + red[1][tid] + red[2][tid] + red[3][tid];
    __syncthreads();

    if (tid < 64){   // wave 0: tile softmax stats
        float s = plds[lane];
        out[ALPHA_OFF + b * Ln + l0 + lane] = s;   // raw score, finalized in k_final
        float m = s;
        m = fmaxf(m, __shfl_xor(m, 1));  m = fmaxf(m, __shfl_xor(m, 2));
        m = fmaxf(m, __shfl_xor(m, 4));  m = fmaxf(m, __shfl_xor(m, 8));
        m = fmaxf(m, __shfl_xor(m, 16)); m = fmaxf(m, __shfl_xor(m, 32));
        float p = __expf(s - m);
        float sm = p;
        sm += __shfl_xor(sm, 1);  sm += __shfl_xor(sm, 2);
        sm += __shfl_xor(sm, 4);  sm += __shfl_xor(sm, 8);
        sm += __shfl_xor(sm, 16); sm += __shfl_xor(sm, 32);
        plds[lane] = p;
        if (lane == 0){ ms_ws[wg * 2] = m; ms_ws[wg * 2 + 1] = sm; }
    }
    __syncthreads();

    // partial awe: pp[ni] = sum over owned rows of p[row]*att1
    float pp[8];
#pragma unroll
    for (int ni = 0; ni < 8; ++ni) pp[ni] = 0.f;
#pragma unroll
    for (int mi = 0; mi < 2; ++mi)
#pragma unroll
        for (int j = 0; j < 4; ++j){
            float pr = plds[wm * 32 + mi * 16 + (lane >> 4) * 4 + j];
#pragma unroll
            for (int ni = 0; ni < 8; ++ni)
                pp[ni] += pr * acc[mi][ni][j];
        }
#pragma unroll
    for (int ni = 0; ni < 8; ++ni){
        pp[ni] += __shfl_xor(pp[ni], 16);
        pp[ni] += __shfl_xor(pp[ni], 32);
    }
    if (lane < 16){
#pragma unroll
        for (int ni = 0; ni < 8; ++ni)
            pawe_lds[wm][wn * 128 + ni * 16 + lane] = pp[ni];
    }
    __syncthreads();
    pawe_ws[(size_t)wg * An + tid] = pawe_lds[0][tid] + pawe_lds[1][tid];
}

// ---------- kernel 2: combine tiles, finalize awe + alpha ----------
__global__ __launch_bounds__(256) void k_final(const float* __restrict__ pawe,
                                               const float* __restrict__ ms,
                                               float* __restrict__ out){
    int b = blockIdx.x, tid = threadIdx.x;
    __shared__ float scale[NTILES];
    __shared__ float sh[2];   // inv_total, global max
    if (tid < 64){
        int lane = tid;
        float m = -1e30f, su = 0.f;
        if (lane < NTILES){ m = ms[(b * NTILES + lane) * 2]; su = ms[(b * NTILES + lane) * 2 + 1]; }
        float mm = m;
        mm = fmaxf(mm, __shfl_xor(mm, 1)); mm = fmaxf(mm, __shfl_xor(mm, 2));
        mm = fmaxf(mm, __shfl_xor(mm, 4)); mm = fmaxf(mm, __shfl_xor(mm, 8));
        float sc = (lane < NTILES) ? su * __expf(m - mm) : 0.f;
        float tot = sc;
        tot += __shfl_xor(tot, 1); tot += __shfl_xor(tot, 2);
        tot += __shfl_xor(tot, 4); tot += __shfl_xor(tot, 8);
        if (lane < NTILES) scale[lane] = __expf(m - mm);
        if (lane == 0){ sh[0] = 1.0f / tot; sh[1] = mm; }
    }
    __syncthreads();
    float inv = sh[0], mm = sh[1];
    for (int a = tid; a < An; a += 256){
        float s = 0.f;
#pragma unroll
        for (int t = 0; t < NTILES; ++t)
            s += pawe[((size_t)(b * NTILES + t)) * An + a] * scale[t];
        out[AWE_OFF + b * An + a] = s * inv;
    }
    for (int l = tid; l < Ln; l += 256){
        float s = out[ALPHA_OFF + b * Ln + l];
        out[ALPHA_OFF + b * Ln + l] = __expf(s - mm) * inv;
    }
}

extern "C" void kernel_launch(void* const* d_in, const int* in_sizes, int n_in,
                              void* d_out, int out_size, void* d_ws, size_t ws_size,
                              hipStream_t stream){
    const float* enc   = (const float*)d_in[0];
    const float* dh    = (const float*)d_in[1];
    const float* Wenc  = (const float*)d_in[2];
    const float* benc  = (const float*)d_in[3];
    const float* Wdec  = (const float*)d_in[4];
    const float* bdec  = (const float*)d_in[5];
    const float* wfull = (const float*)d_in[6];
    // d_in[7] = b_full: softmax-invariant, unused.
    float* out = (float*)d_out;

    char* ws = (char*)d_ws;
    unsigned short* Wp = (unsigned short*)ws;                       // 2 MB packed W
    float* att2 = (float*)(ws + (2u << 20));                        // 128 KB
    float* pawe = (float*)(ws + (2u << 20) + (128u << 10));         // 2 MB
    float* msb  = (float*)(ws + (4u << 20) + (128u << 10));         // 8 KB

    k_pack<<<512, 256, 0, stream>>>(Wenc, Wp);
    k_att2<<<Bn, 256, 0, stream>>>(dh, Wdec, bdec, att2);
    k_main<<<Bn * NTILES, 512, 0, stream>>>(enc, Wp, benc, att2, wfull, out, pawe, msb);
    k_final<<<Bn, 256, 0, stream>>>(pawe, msb, out);
}

// Round 4
// 289.702 us; speedup vs baseline: 2.1701x; 1.6684x over previous
//
#include <hip/hip_runtime.h>
#include <hip/hip_bf16.h>

// Fused additive-attention (Bahdanau-style) on MI355X.
//   att1 = enc @ W_enc + b_enc            [B,L,A]  (bf16 MFMA, fp32 accum)
//   att2 = dh @ W_dec + b_dec             [B,A]
//   s    = tanh(att1+att2) . W_full       [B,L]    (b_full dropped: softmax-invariant)
//   alpha= softmax_L(s); awe = sum_l alpha * att1  [B,A]
// Flash-style two-level softmax: each (b, l-tile of 64) wg emits
// (m_tile, sum_tile, pawe[512]); att1 never hits HBM.
//
// R4 = R3 with the A-fragment swizzle bug fixed:
//   s=1 fragment offset must be (64+akb)^sw, NOT (akb^sw)+64 (differs when
//   sw bit6 is set -> cross-row read -> NaN). Carry two base pointers per
//   LDS buffer. alignas(16) on LDS tiles for ds_read_b128.
// R3 levers kept: 1024-thr blocks (16 waves, wave = 64 rows x 32 cols,
//   acc=32 AGPR -> 4 waves/SIMD), per-phase VMEM issue order
//   [B loads (L2) -> enc prefetch (HBM) -> stage -> MFMA], fast tanh.

#define Bn 64
#define Ln 1024
#define En 2048
#define An 512
#define TM 64          // l-rows per workgroup
#define NTILES (Ln/TM) // 16
#define AWE_OFF 0
#define ALPHA_OFF (Bn*An) // 32768

using short8 = __attribute__((ext_vector_type(8))) short;
using sh4    = __attribute__((ext_vector_type(4))) short;
using f32x4  = __attribute__((ext_vector_type(4))) float;

__device__ inline short f2bf(float x){
    unsigned u = __builtin_bit_cast(unsigned, x);
    unsigned r = (u + 0x7fffu + ((u >> 16) & 1u)) >> 16;
    return (short)r;
}
__device__ inline float tanh_fast(float x){
    // 2/(1+e^{-2x}) - 1 ; saturates correctly for |x| large (no inf/inf)
    return 2.0f * __frcp_rn(1.0f + __expf(-2.0f * x)) - 1.0f;
}

// ---------- kernel 0a: pack W_enc into MFMA B-fragment layout ----------
// frag f = kb*32 + nc  (kb: k-block of 32, nc: col-block of 16)
// Wp[f*512 + lane*8 + j] = bf16(W[kb*32 + (lane>>4)*8 + j][nc*16 + (lane&15)])
__global__ __launch_bounds__(256) void k_pack(const float* __restrict__ W,
                                              unsigned short* __restrict__ Wp){
    int t = blockIdx.x * 256 + threadIdx.x;   // 512 wgs * 256 = 2048 frags * 64 lanes
    int f = t >> 6, lane = t & 63;
    int kb = f >> 5, nc = f & 31;
    int k0 = kb * 32 + (lane >> 4) * 8;
    int col = nc * 16 + (lane & 15);
    short8 v;
#pragma unroll
    for (int j = 0; j < 8; ++j)
        v[j] = f2bf(W[(size_t)(k0 + j) * An + col]);
    *(short8*)(Wp + (size_t)f * 512 + lane * 8) = v;
}

// ---------- kernel 0b: att2[b][a] = dh[b] @ W_dec[:,a] + b_dec[a] ----------
__global__ __launch_bounds__(256) void k_att2(const float* __restrict__ dh,
                                              const float* __restrict__ Wd,
                                              const float* __restrict__ bd,
                                              float* __restrict__ att2){
    int b = blockIdx.x, tid = threadIdx.x;
    __shared__ float dl[512];
    dl[tid]       = dh[b * 512 + tid];
    dl[tid + 256] = dh[b * 512 + tid + 256];
    __syncthreads();
    for (int a = tid; a < An; a += 256){
        float s = bd[a];
        for (int k = 0; k < 512; ++k)
            s = fmaf(dl[k], Wd[(size_t)k * An + a], s);
        att2[b * An + a] = s;
    }
}

// ---------- kernel 1: fused GEMM + score + tile-softmax + partial awe ----------
// 1024 threads = 16 waves, wave w owns rows 0..63 x cols [w*32, w*32+32).
// acc[mi][ni]: mi = row block (mi*16), ni = col block (w*32 + ni*16).

#define MFMA(a, b, c) __builtin_amdgcn_mfma_f32_16x16x32_bf16((a), (b), (c), 0, 0, 0)

// One 64-wide K phase. Issue order matters (in-order vmcnt):
//   B loads (L2) -> enc prefetch (HBM, tile P+2) -> stage tile P+1 (waits
//   prev-phase enc) -> ds_read + MFMA (waits only the B loads).
// AB0/AB1: this buffer's A-fragment base for k-half s=0 / s=1 (both swizzled).
#define PHASE(P, AB0, AB1, NXT, RC, RN)                                       \
{                                                                             \
    __syncthreads();                                                          \
    const unsigned short* bp = Bbase + (P) * 32768;                           \
    short8 bf00 = *(const short8*)(bp);                                       \
    short8 bf01 = *(const short8*)(bp + 512);                                 \
    short8 bf10 = *(const short8*)(bp + 16384);                               \
    short8 bf11 = *(const short8*)(bp + 16384 + 512);                         \
    if ((P) + 2 < 32)                                                         \
        RN = *(const float4*)(apt + ((P) + 2) * 64);                          \
    if ((P) + 1 < 32){                                                        \
        sh4 sv;                                                               \
        sv[0] = f2bf(RC.x); sv[1] = f2bf(RC.y);                               \
        sv[2] = f2bf(RC.z); sv[3] = f2bf(RC.w);                               \
        *(sh4*)((NXT) + sbyte) = sv;                                          \
    }                                                                         \
    _Pragma("unroll")                                                         \
    for (int mi = 0; mi < 4; ++mi){                                           \
        short8 af0 = *(const short8*)((AB0) + mi * 2048);                     \
        short8 af1 = *(const short8*)((AB1) + mi * 2048);                     \
        acc[mi][0] = MFMA(af0, bf00, acc[mi][0]);                             \
        acc[mi][1] = MFMA(af0, bf01, acc[mi][1]);                             \
        acc[mi][0] = MFMA(af1, bf10, acc[mi][0]);                             \
        acc[mi][1] = MFMA(af1, bf11, acc[mi][1]);                             \
    }                                                                         \
}

__global__ __launch_bounds__(1024)
void k_main(const float* __restrict__ enc, const unsigned short* __restrict__ Wp,
            const float* __restrict__ benc, const float* __restrict__ att2,
            const float* __restrict__ wfull, float* __restrict__ out,
            float* __restrict__ pawe_ws, float* __restrict__ ms_ws){
    const int wg   = blockIdx.x;            // 0..1023
    const int b    = wg >> 4;
    const int tile = wg & 15;
    const int l0   = tile * TM;
    const int tid  = threadIdx.x;
    const int lane = tid & 63, w = tid >> 6;   // w = 0..15

    __shared__ alignas(16) unsigned short Alds0[TM * 64];  // 8 KB each, XOR-swizzled bf16
    __shared__ alignas(16) unsigned short Alds1[TM * 64];
    __shared__ float red[16][TM];              // per-wave row score partials
    __shared__ float plds[TM];                 // tile-local exp(s - m)
    char* const alds0 = (char*)Alds0;
    char* const alds1 = (char*)Alds1;

    f32x4 acc[4][2];
#pragma unroll
    for (int mi = 0; mi < 4; ++mi)
#pragma unroll
        for (int ni = 0; ni < 2; ++ni)
            acc[mi][ni] = (f32x4){0.f, 0.f, 0.f, 0.f};

    // staging: thread loads 4 fp32 (16B) of row (tid>>4), k-chunk (tid&15)*4
    const int srow  = tid >> 4;
    const int sbyte = srow * 128 + (((tid & 15) * 8) ^ ((srow & 7) << 4));
    const float* apt = enc + ((size_t)(b * Ln + l0 + srow)) * En + (tid & 15) * 4;

    // B fragments: f = (p*2+s)*32 + w*2 + ni ; addr = Wp + f*512 + lane*8
    const unsigned short* Bbase = Wp + (size_t)(w * 2) * 512 + lane * 8;

    // A fragments: row = mi*16 + (lane&15); k-byte = (s*64 + akb) ^ sw  (full XOR!)
    const int arow = lane & 15;
    const int akb  = (lane >> 4) * 16;
    const int sw   = (arow & 7) << 4;
    const int off0 = akb ^ sw;            // s=0 k-half
    const int off1 = (64 + akb) ^ sw;     // s=1 k-half  (NOT off0+64!)
    const char* a0s0 = alds0 + arow * 128 + off0;
    const char* a0s1 = alds0 + arow * 128 + off1;
    const char* a1s0 = alds1 + arow * 128 + off0;
    const char* a1s1 = alds1 + arow * 128 + off1;

    // prologue: tile0 -> LDS0, tile1 -> rc
    float4 rc = *(const float4*)(apt);
    {
        sh4 sv;
        sv[0] = f2bf(rc.x); sv[1] = f2bf(rc.y); sv[2] = f2bf(rc.z); sv[3] = f2bf(rc.w);
        *(sh4*)(alds0 + sbyte) = sv;
    }
    rc = *(const float4*)(apt + 64);
    float4 rn = rc;

    for (int p = 0; p < 32; p += 2){
        PHASE(p,     a0s0, a0s1, alds1, rc, rn)
        PHASE(p + 1, a1s0, a1s1, alds0, rn, rc)
    }

    // ---- epilogue ----
    float be[2], a2[2], wfv[2];
    const int cbase = w * 32 + (lane & 15);
#pragma unroll
    for (int ni = 0; ni < 2; ++ni){
        int c = cbase + ni * 16;
        be[ni]  = benc[c];
        a2[ni]  = att2[b * An + c];
        wfv[ni] = wfull[c];
    }

    float tsum[4][4];
#pragma unroll
    for (int mi = 0; mi < 4; ++mi)
#pragma unroll
        for (int j = 0; j < 4; ++j)
            tsum[mi][j] = 0.f;
#pragma unroll
    for (int mi = 0; mi < 4; ++mi)
#pragma unroll
        for (int ni = 0; ni < 2; ++ni)
#pragma unroll
            for (int j = 0; j < 4; ++j){
                float vv = acc[mi][ni][j] + be[ni];
                acc[mi][ni][j] = vv;
                tsum[mi][j] += tanh_fast(vv + a2[ni]) * wfv[ni];
            }

    // reduce across the 16 lanes of each row-group, stash per-wave partials
#pragma unroll
    for (int mi = 0; mi < 4; ++mi)
#pragma unroll
        for (int j = 0; j < 4; ++j){
            float t = tsum[mi][j];
            t += __shfl_xor(t, 1); t += __shfl_xor(t, 2);
            t += __shfl_xor(t, 4); t += __shfl_xor(t, 8);
            if ((lane & 15) == 0)
                red[w][mi * 16 + (lane >> 4) * 4 + j] = t;
        }
    __syncthreads();

    if (tid < 64){   // wave 0: combine 16 wave-partials, tile softmax stats
        float s = 0.f;
#pragma unroll
        for (int k = 0; k < 16; ++k)
            s += red[k][tid];
        out[ALPHA_OFF + b * Ln + l0 + tid] = s;   // raw score; finalized in k_final
        float m = s;
        m = fmaxf(m, __shfl_xor(m, 1));  m = fmaxf(m, __shfl_xor(m, 2));
        m = fmaxf(m, __shfl_xor(m, 4));  m = fmaxf(m, __shfl_xor(m, 8));
        m = fmaxf(m, __shfl_xor(m, 16)); m = fmaxf(m, __shfl_xor(m, 32));
        float pv = __expf(s - m);
        float sm = pv;
        sm += __shfl_xor(sm, 1);  sm += __shfl_xor(sm, 2);
        sm += __shfl_xor(sm, 4);  sm += __shfl_xor(sm, 8);
        sm += __shfl_xor(sm, 16); sm += __shfl_xor(sm, 32);
        plds[tid] = pv;
        if (tid == 0){ ms_ws[wg * 2] = m; ms_ws[wg * 2 + 1] = sm; }
    }
    __syncthreads();

    // partial awe for this wave's 32 cols (rows complete within the wave)
    float pp0 = 0.f, pp1 = 0.f;
#pragma unroll
    for (int mi = 0; mi < 4; ++mi)
#pragma unroll
        for (int j = 0; j < 4; ++j){
            float pr = plds[mi * 16 + (lane >> 4) * 4 + j];
            pp0 += pr * acc[mi][0][j];
            pp1 += pr * acc[mi][1][j];
        }
    pp0 += __shfl_xor(pp0, 16); pp0 += __shfl_xor(pp0, 32);
    pp1 += __shfl_xor(pp1, 16); pp1 += __shfl_xor(pp1, 32);
    if (lane < 16){
        pawe_ws[(size_t)wg * An + w * 32 + lane]      = pp0;
        pawe_ws[(size_t)wg * An + w * 32 + 16 + lane] = pp1;
    }
}

// ---------- kernel 2: combine tiles, finalize awe + alpha ----------
__global__ __launch_bounds__(256) void k_final(const float* __restrict__ pawe,
                                               const float* __restrict__ ms,
                                               float* __restrict__ out){
    int b = blockIdx.x, tid = threadIdx.x;
    __shared__ float scale[NTILES];
    __shared__ float sh[2];   // inv_total, global max
    if (tid < 64){
        int lane = tid;
        float m = -1e30f, su = 0.f;
        if (lane < NTILES){ m = ms[(b * NTILES + lane) * 2]; su = ms[(b * NTILES + lane) * 2 + 1]; }
        float mm = m;
        mm = fmaxf(mm, __shfl_xor(mm, 1)); mm = fmaxf(mm, __shfl_xor(mm, 2));
        mm = fmaxf(mm, __shfl_xor(mm, 4)); mm = fmaxf(mm, __shfl_xor(mm, 8));
        float sc = (lane < NTILES) ? su * __expf(m - mm) : 0.f;
        float tot = sc;
        tot += __shfl_xor(tot, 1); tot += __shfl_xor(tot, 2);
        tot += __shfl_xor(tot, 4); tot += __shfl_xor(tot, 8);
        if (lane < NTILES) scale[lane] = __expf(m - mm);
        if (lane == 0){ sh[0] = 1.0f / tot; sh[1] = mm; }
    }
    __syncthreads();
    float inv = sh[0], mm = sh[1];
    for (int a = tid; a < An; a += 256){
        float s = 0.f;
#pragma unroll
        for (int t = 0; t < NTILES; ++t)
            s += pawe[((size_t)(b * NTILES + t)) * An + a] * scale[t];
        out[AWE_OFF + b * An + a] = s * inv;
    }
    for (int l = tid; l < Ln; l += 256){
        float s = out[ALPHA_OFF + b * Ln + l];
        out[ALPHA_OFF + b * Ln + l] = __expf(s - mm) * inv;
    }
}

extern "C" void kernel_launch(void* const* d_in, const int* in_sizes, int n_in,
                              void* d_out, int out_size, void* d_ws, size_t ws_size,
                              hipStream_t stream){
    const float* enc   = (const float*)d_in[0];
    const float* dh    = (const float*)d_in[1];
    const float* Wenc  = (const float*)d_in[2];
    const float* benc  = (const float*)d_in[3];
    const float* Wdec  = (const float*)d_in[4];
    const float* bdec  = (const float*)d_in[5];
    const float* wfull = (const float*)d_in[6];
    // d_in[7] = b_full: softmax-invariant, unused.
    float* out = (float*)d_out;

    char* ws = (char*)d_ws;
    unsigned short* Wp = (unsigned short*)ws;                       // 2 MB packed W
    float* att2 = (float*)(ws + (2u << 20));                        // 128 KB
    float* pawe = (float*)(ws + (2u << 20) + (128u << 10));         // 2 MB
    float* msb  = (float*)(ws + (4u << 20) + (128u << 10));         // 8 KB

    k_pack<<<512, 256, 0, stream>>>(Wenc, Wp);
    k_att2<<<Bn, 256, 0, stream>>>(dh, Wdec, bdec, att2);
    k_main<<<Bn * NTILES, 1024, 0, stream>>>(enc, Wp, benc, att2, wfull, out, pawe, msb);
    k_final<<<Bn, 256, 0, stream>>>(pawe, msb, out);
}

// Round 5
// 253.557 us; speedup vs baseline: 2.4795x; 1.1426x over previous
//
#include <hip/hip_runtime.h>
#include <hip/hip_bf16.h>

// Fused additive-attention (Bahdanau-style) on MI355X.
//   att1 = enc @ W_enc + b_enc            [B,L,A]  (bf16 MFMA, fp32 accum)
//   att2 = dh @ W_dec + b_dec             [B,A]
//   s    = tanh(att1+att2) . W_full       [B,L]    (b_full dropped: softmax-invariant)
//   alpha= softmax_L(s); awe = sum_l alpha * att1  [B,A]
// Flash-style two-level softmax: each (b, l-tile of 64) wg emits
// (m_tile, sum_tile, pawe[512]); att1 never hits HBM.
//
// R5 vs R4 (290us total, k_main ~230us, latency-bound at 1 block/CU):
//  - Quad-buffered A-LDS (4 x 8KB, one base + imm offsets): barrier every
//    2 phases instead of every phase -> half the barrier drains, waves can
//    skew within the 2-phase window.
//  - enc prefetch slack 1 -> 2 phases at SAME register cost (2 float4):
//    stage both tiles of the next superphase at one point, reload both.
//  - k_pack + k_att2 merged into one launch (k_prep).

#define Bn 64
#define Ln 1024
#define En 2048
#define An 512
#define TM 64          // l-rows per workgroup
#define NTILES (Ln/TM) // 16
#define AWE_OFF 0
#define ALPHA_OFF (Bn*An) // 32768
#define TILEB 8192     // bytes per A k-tile LDS buffer

using short8 = __attribute__((ext_vector_type(8))) short;
using sh4    = __attribute__((ext_vector_type(4))) short;
using f32x4  = __attribute__((ext_vector_type(4))) float;

__device__ inline short f2bf(float x){
    unsigned u = __builtin_bit_cast(unsigned, x);
    unsigned r = (u + 0x7fffu + ((u >> 16) & 1u)) >> 16;
    return (short)r;
}
__device__ inline float tanh_fast(float x){
    return 2.0f * __frcp_rn(1.0f + __expf(-2.0f * x)) - 1.0f;
}

// ---------- kernel 0: W_enc fragment-pack  +  att2 GEMV (merged) ----------
// blocks 0..511: Wp[f*512 + lane*8 + j] = bf16(W[kb*32+(lane>>4)*8+j][nc*16+(lane&15)])
// blocks 512..575: att2[b][a] = dh[b] @ W_dec[:,a] + b_dec[a]
__global__ __launch_bounds__(256) void k_prep(const float* __restrict__ W,
                                              unsigned short* __restrict__ Wp,
                                              const float* __restrict__ dh,
                                              const float* __restrict__ Wd,
                                              const float* __restrict__ bd,
                                              float* __restrict__ att2){
    __shared__ float dl[512];
    int blk = blockIdx.x, tid = threadIdx.x;
    if (blk < 512){
        int t = blk * 256 + tid;
        int f = t >> 6, lane = t & 63;
        int kb = f >> 5, nc = f & 31;
        int k0 = kb * 32 + (lane >> 4) * 8;
        int col = nc * 16 + (lane & 15);
        short8 v;
#pragma unroll
        for (int j = 0; j < 8; ++j)
            v[j] = f2bf(W[(size_t)(k0 + j) * An + col]);
        *(short8*)(Wp + (size_t)f * 512 + lane * 8) = v;
    } else {
        int b = blk - 512;
        dl[tid]       = dh[b * 512 + tid];
        dl[tid + 256] = dh[b * 512 + tid + 256];
        __syncthreads();
        for (int a = tid; a < An; a += 256){
            float s = bd[a];
            for (int k = 0; k < 512; ++k)
                s = fmaf(dl[k], Wd[(size_t)k * An + a], s);
            att2[b * An + a] = s;
        }
    }
}

// ---------- kernel 1: fused GEMM + score + tile-softmax + partial awe ----------
// 1024 threads = 16 waves, wave w owns rows 0..63 x cols [w*32, w*32+32).

#define MFMA(a, b, c) __builtin_amdgcn_mfma_f32_16x16x32_bf16((a), (b), (c), 0, 0, 0)

#define BLOAD(P)                                                              \
    const unsigned short* bp = Bbase + (size_t)(P) * 32768;                   \
    short8 bf00 = *(const short8*)(bp);                                       \
    short8 bf01 = *(const short8*)(bp + 512);                                 \
    short8 bf10 = *(const short8*)(bp + 16384);                               \
    short8 bf11 = *(const short8*)(bp + 16384 + 512);

#define STAGE(Q, R)                                                           \
    { sh4 sv;                                                                 \
      sv[0] = f2bf(R.x); sv[1] = f2bf(R.y);                                   \
      sv[2] = f2bf(R.z); sv[3] = f2bf(R.w);                                   \
      *(sh4*)(swp + (Q) * TILEB) = sv; }

#define MFMAS(Q)                                                              \
    _Pragma("unroll")                                                         \
    for (int mi = 0; mi < 4; ++mi){                                           \
        short8 af0 = *(const short8*)(as0 + (Q) * TILEB + mi * 2048);         \
        short8 af1 = *(const short8*)(as1 + (Q) * TILEB + mi * 2048);         \
        acc[mi][0] = MFMA(af0, bf00, acc[mi][0]);                             \
        acc[mi][1] = MFMA(af0, bf01, acc[mi][1]);                             \
        acc[mi][0] = MFMA(af1, bf10, acc[mi][0]);                             \
        acc[mi][1] = MFMA(af1, bf11, acc[mi][1]);                             \
    }

__global__ __launch_bounds__(1024)
void k_main(const float* __restrict__ enc, const unsigned short* __restrict__ Wp,
            const float* __restrict__ benc, const float* __restrict__ att2,
            const float* __restrict__ wfull, float* __restrict__ out,
            float* __restrict__ pawe_ws, float* __restrict__ ms_ws){
    const int wg   = blockIdx.x;            // 0..1023
    const int b    = wg >> 4;
    const int tile = wg & 15;
    const int l0   = tile * TM;
    const int tid  = threadIdx.x;
    const int lane = tid & 63, w = tid >> 6;   // w = 0..15

    __shared__ alignas(16) unsigned short Alds[4][TM * 64];  // 4 x 8 KB, XOR-swizzled bf16
    __shared__ float red[16][TM];              // per-wave row score partials
    __shared__ float plds[TM];                 // tile-local exp(s - m)
    char* const alds = (char*)Alds;

    f32x4 acc[4][2];
#pragma unroll
    for (int mi = 0; mi < 4; ++mi)
#pragma unroll
        for (int ni = 0; ni < 2; ++ni)
            acc[mi][ni] = (f32x4){0.f, 0.f, 0.f, 0.f};

    // staging: thread loads 4 fp32 (16B) of row (tid>>4), k-chunk (tid&15)*4
    const int srow  = tid >> 4;
    const int sbyte = srow * 128 + (((tid & 15) * 8) ^ ((srow & 7) << 4));
    char* const swp = alds + sbyte;
    const float* apt = enc + ((size_t)(b * Ln + l0 + srow)) * En + (tid & 15) * 4;

    // B fragments: f = (p*2+s)*32 + w*2 + ni ; addr = Wp + f*512 + lane*8
    const unsigned short* Bbase = Wp + (size_t)(w * 2) * 512 + lane * 8;

    // A fragments: row = mi*16 + (lane&15); k-byte = (s*64 + akb) ^ sw (full XOR)
    const int arow = lane & 15;
    const int akb  = (lane >> 4) * 16;
    const int sw   = (arow & 7) << 4;
    const char* const as0 = alds + arow * 128 + (akb ^ sw);
    const char* const as1 = alds + arow * 128 + ((64 + akb) ^ sw);

    // prologue: tiles 0,1 staged; ring ra,rb holds tiles 2,3
    float4 ra = *(const float4*)(apt);
    float4 rb = *(const float4*)(apt + 64);
    STAGE(0, ra)
    STAGE(1, rb)
    ra = *(const float4*)(apt + 2 * 64);
    rb = *(const float4*)(apt + 3 * 64);

    for (int p = 0; p < 32; p += 4){
        __syncthreads();
        {   // phase p: compute Q0; stage tiles p+2,p+3 -> Q2,Q3; reload ring
            BLOAD(p)
            STAGE(2, ra)
            STAGE(3, rb)
            int t0 = p + 4 > 31 ? 31 : p + 4;   // clamped tail loads (unread)
            int t1 = p + 5 > 31 ? 31 : p + 5;
            ra = *(const float4*)(apt + t0 * 64);
            rb = *(const float4*)(apt + t1 * 64);
            MFMAS(0)
        }
        {   // phase p+1: compute Q1
            BLOAD(p + 1)
            MFMAS(1)
        }
        __syncthreads();
        {   // phase p+2: compute Q2; stage tiles p+4,p+5 -> Q0,Q1; reload ring
            BLOAD(p + 2)
            STAGE(0, ra)
            STAGE(1, rb)
            int t0 = p + 6 > 31 ? 31 : p + 6;
            int t1 = p + 7 > 31 ? 31 : p + 7;
            ra = *(const float4*)(apt + t0 * 64);
            rb = *(const float4*)(apt + t1 * 64);
            MFMAS(2)
        }
        {   // phase p+3: compute Q3
            BLOAD(p + 3)
            MFMAS(3)
        }
    }

    // ---- epilogue ----
    float be[2], a2[2], wfv[2];
    const int cbase = w * 32 + (lane & 15);
#pragma unroll
    for (int ni = 0; ni < 2; ++ni){
        int c = cbase + ni * 16;
        be[ni]  = benc[c];
        a2[ni]  = att2[b * An + c];
        wfv[ni] = wfull[c];
    }

    float tsum[4][4];
#pragma unroll
    for (int mi = 0; mi < 4; ++mi)
#pragma unroll
        for (int j = 0; j < 4; ++j)
            tsum[mi][j] = 0.f;
#pragma unroll
    for (int mi = 0; mi < 4; ++mi)
#pragma unroll
        for (int ni = 0; ni < 2; ++ni)
#pragma unroll
            for (int j = 0; j < 4; ++j){
                float vv = acc[mi][ni][j] + be[ni];
                acc[mi][ni][j] = vv;
                tsum[mi][j] += tanh_fast(vv + a2[ni]) * wfv[ni];
            }

#pragma unroll
    for (int mi = 0; mi < 4; ++mi)
#pragma unroll
        for (int j = 0; j < 4; ++j){
            float t = tsum[mi][j];
            t += __shfl_xor(t, 1); t += __shfl_xor(t, 2);
            t += __shfl_xor(t, 4); t += __shfl_xor(t, 8);
            if ((lane & 15) == 0)
                red[w][mi * 16 + (lane >> 4) * 4 + j] = t;
        }
    __syncthreads();

    if (tid < 64){   // wave 0: combine 16 wave-partials, tile softmax stats
        float s = 0.f;
#pragma unroll
        for (int k = 0; k < 16; ++k)
            s += red[k][tid];
        out[ALPHA_OFF + b * Ln + l0 + tid] = s;   // raw score; finalized in k_final
        float m = s;
        m = fmaxf(m, __shfl_xor(m, 1));  m = fmaxf(m, __shfl_xor(m, 2));
        m = fmaxf(m, __shfl_xor(m, 4));  m = fmaxf(m, __shfl_xor(m, 8));
        m = fmaxf(m, __shfl_xor(m, 16)); m = fmaxf(m, __shfl_xor(m, 32));
        float pv = __expf(s - m);
        float sm = pv;
        sm += __shfl_xor(sm, 1);  sm += __shfl_xor(sm, 2);
        sm += __shfl_xor(sm, 4);  sm += __shfl_xor(sm, 8);
        sm += __shfl_xor(sm, 16); sm += __shfl_xor(sm, 32);
        plds[tid] = pv;
        if (tid == 0){ ms_ws[wg * 2] = m; ms_ws[wg * 2 + 1] = sm; }
    }
    __syncthreads();

    // partial awe for this wave's 32 cols (rows complete within the wave)
    float pp0 = 0.f, pp1 = 0.f;
#pragma unroll
    for (int mi = 0; mi < 4; ++mi)
#pragma unroll
        for (int j = 0; j < 4; ++j){
            float pr = plds[mi * 16 + (lane >> 4) * 4 + j];
            pp0 += pr * acc[mi][0][j];
            pp1 += pr * acc[mi][1][j];
        }
    pp0 += __shfl_xor(pp0, 16); pp0 += __shfl_xor(pp0, 32);
    pp1 += __shfl_xor(pp1, 16); pp1 += __shfl_xor(pp1, 32);
    if (lane < 16){
        pawe_ws[(size_t)wg * An + w * 32 + lane]      = pp0;
        pawe_ws[(size_t)wg * An + w * 32 + 16 + lane] = pp1;
    }
}

// ---------- kernel 2: combine tiles, finalize awe + alpha ----------
__global__ __launch_bounds__(256) void k_final(const float* __restrict__ pawe,
                                               const float* __restrict__ ms,
                                               float* __restrict__ out){
    int b = blockIdx.x, tid = threadIdx.x;
    __shared__ float scale[NTILES];
    __shared__ float sh[2];   // inv_total, global max
    if (tid < 64){
        int lane = tid;
        float m = -1e30f, su = 0.f;
        if (lane < NTILES){ m = ms[(b * NTILES + lane) * 2]; su = ms[(b * NTILES + lane) * 2 + 1]; }
        float mm = m;
        mm = fmaxf(mm, __shfl_xor(mm, 1)); mm = fmaxf(mm, __shfl_xor(mm, 2));
        mm = fmaxf(mm, __shfl_xor(mm, 4)); mm = fmaxf(mm, __shfl_xor(mm, 8));
        float sc = (lane < NTILES) ? su * __expf(m - mm) : 0.f;
        float tot = sc;
        tot += __shfl_xor(tot, 1); tot += __shfl_xor(tot, 2);
        tot += __shfl_xor(tot, 4); tot += __shfl_xor(tot, 8);
        if (lane < NTILES) scale[lane] = __expf(m - mm);
        if (lane == 0){ sh[0] = 1.0f / tot; sh[1] = mm; }
    }
    __syncthreads();
    float inv = sh[0], mm = sh[1];
    for (int a = tid; a < An; a += 256){
        float s = 0.f;
#pragma unroll
        for (int t = 0; t < NTILES; ++t)
            s += pawe[((size_t)(b * NTILES + t)) * An + a] * scale[t];
        out[AWE_OFF + b * An + a] = s * inv;
    }
    for (int l = tid; l < Ln; l += 256){
        float s = out[ALPHA_OFF + b * Ln + l];
        out[ALPHA_OFF + b * Ln + l] = __expf(s - mm) * inv;
    }
}

extern "C" void kernel_launch(void* const* d_in, const int* in_sizes, int n_in,
                              void* d_out, int out_size, void* d_ws, size_t ws_size,
                              hipStream_t stream){
    const float* enc   = (const float*)d_in[0];
    const float* dh    = (const float*)d_in[1];
    const float* Wenc  = (const float*)d_in[2];
    const float* benc  = (const float*)d_in[3];
    const float* Wdec  = (const float*)d_in[4];
    const float* bdec  = (const float*)d_in[5];
    const float* wfull = (const float*)d_in[6];
    // d_in[7] = b_full: softmax-invariant, unused.
    float* out = (float*)d_out;

    char* ws = (char*)d_ws;
    unsigned short* Wp = (unsigned short*)ws;                       // 2 MB packed W
    float* att2 = (float*)(ws + (2u << 20));                        // 128 KB
    float* pawe = (float*)(ws + (2u << 20) + (128u << 10));         // 2 MB
    float* msb  = (float*)(ws + (4u << 20) + (128u << 10));         // 8 KB

    k_prep<<<576, 256, 0, stream>>>(Wenc, Wp, dh, Wdec, bdec, att2);
    k_main<<<Bn * NTILES, 1024, 0, stream>>>(enc, Wp, benc, att2, wfull, out, pawe, msb);
    k_final<<<Bn, 256, 0, stream>>>(pawe, msb, out);
}

// Round 6
// 246.826 us; speedup vs baseline: 2.5471x; 1.0273x over previous
//
#include <hip/hip_runtime.h>
#include <hip/hip_bf16.h>

// Fused additive-attention (Bahdanau-style) on MI355X.
//   att1 = enc @ W_enc + b_enc            [B,L,A]  (bf16 MFMA, fp32 accum)
//   att2 = dh @ W_dec + b_dec             [B,A]
//   s    = tanh(att1+att2) . W_full       [B,L]    (b_full dropped: softmax-invariant)
//   alpha= softmax_L(s); awe = sum_l alpha * att1  [B,A]
// Flash-style two-level softmax: each (b, l-tile of 64) wg emits
// (m_tile, sum_tile, pawe[512]); att1 never hits HBM.
//
// R6 vs R5 (253.6us): B-fragment register prefetch one phase ahead
// (two alternating bf reg sets, +16 VGPR ~= 124 total, still 4 waves/SIMD).
// Per-phase issue order: [next-phase B loads] -> [enc stage (2-phase-old
// data)] -> [MFMAs on PREVIOUS phase's B, already landed]. Removes the
// ~300-500cyc L2 wait that stalled every lockstepped wave at每 phase start.

#define Bn 64
#define Ln 1024
#define En 2048
#define An 512
#define TM 64          // l-rows per workgroup
#define NTILES (Ln/TM) // 16
#define AWE_OFF 0
#define ALPHA_OFF (Bn*An) // 32768
#define TILEB 8192     // bytes per A k-tile LDS buffer

using short8 = __attribute__((ext_vector_type(8))) short;
using sh4    = __attribute__((ext_vector_type(4))) short;
using f32x4  = __attribute__((ext_vector_type(4))) float;

__device__ inline short f2bf(float x){
    unsigned u = __builtin_bit_cast(unsigned, x);
    unsigned r = (u + 0x7fffu + ((u >> 16) & 1u)) >> 16;
    return (short)r;
}
__device__ inline float tanh_fast(float x){
    return 2.0f * __frcp_rn(1.0f + __expf(-2.0f * x)) - 1.0f;
}

// ---------- kernel 0: W_enc fragment-pack  +  att2 GEMV (merged) ----------
__global__ __launch_bounds__(256) void k_prep(const float* __restrict__ W,
                                              unsigned short* __restrict__ Wp,
                                              const float* __restrict__ dh,
                                              const float* __restrict__ Wd,
                                              const float* __restrict__ bd,
                                              float* __restrict__ att2){
    __shared__ float dl[512];
    int blk = blockIdx.x, tid = threadIdx.x;
    if (blk < 512){
        int t = blk * 256 + tid;
        int f = t >> 6, lane = t & 63;
        int kb = f >> 5, nc = f & 31;
        int k0 = kb * 32 + (lane >> 4) * 8;
        int col = nc * 16 + (lane & 15);
        short8 v;
#pragma unroll
        for (int j = 0; j < 8; ++j)
            v[j] = f2bf(W[(size_t)(k0 + j) * An + col]);
        *(short8*)(Wp + (size_t)f * 512 + lane * 8) = v;
    } else {
        int b = blk - 512;
        dl[tid]       = dh[b * 512 + tid];
        dl[tid + 256] = dh[b * 512 + tid + 256];
        __syncthreads();
        for (int a = tid; a < An; a += 256){
            float s = bd[a];
            for (int k = 0; k < 512; ++k)
                s = fmaf(dl[k], Wd[(size_t)k * An + a], s);
            att2[b * An + a] = s;
        }
    }
}

// ---------- kernel 1: fused GEMM + score + tile-softmax + partial awe ----------
// 1024 threads = 16 waves, wave w owns rows 0..63 x cols [w*32, w*32+32).

#define MFMA(a, b, c) __builtin_amdgcn_mfma_f32_16x16x32_bf16((a), (b), (c), 0, 0, 0)

// Issue next-phase B loads into register set S (S = A or B).
#define BLOAD(S, P)                                                           \
    { int pc = (P) > 31 ? 31 : (P);                                           \
      const unsigned short* bp = Bbase + (size_t)pc * 32768;                  \
      S##00 = *(const short8*)(bp);                                           \
      S##01 = *(const short8*)(bp + 512);                                     \
      S##10 = *(const short8*)(bp + 16384);                                   \
      S##11 = *(const short8*)(bp + 16384 + 512); }

#define STAGE(Q, R)                                                           \
    { sh4 sv;                                                                 \
      sv[0] = f2bf(R.x); sv[1] = f2bf(R.y);                                   \
      sv[2] = f2bf(R.z); sv[3] = f2bf(R.w);                                   \
      *(sh4*)(swp + (Q) * TILEB) = sv; }

// MFMAs for buffer Q using register set S (already landed).
#define MFMAS(Q, S)                                                           \
    _Pragma("unroll")                                                         \
    for (int mi = 0; mi < 4; ++mi){                                           \
        short8 af0 = *(const short8*)(as0 + (Q) * TILEB + mi * 2048);         \
        short8 af1 = *(const short8*)(as1 + (Q) * TILEB + mi * 2048);         \
        acc[mi][0] = MFMA(af0, S##00, acc[mi][0]);                            \
        acc[mi][1] = MFMA(af0, S##01, acc[mi][1]);                            \
        acc[mi][0] = MFMA(af1, S##10, acc[mi][0]);                            \
        acc[mi][1] = MFMA(af1, S##11, acc[mi][1]);                            \
    }

__global__ __launch_bounds__(1024)
void k_main(const float* __restrict__ enc, const unsigned short* __restrict__ Wp,
            const float* __restrict__ benc, const float* __restrict__ att2,
            const float* __restrict__ wfull, float* __restrict__ out,
            float* __restrict__ pawe_ws, float* __restrict__ ms_ws){
    const int wg   = blockIdx.x;            // 0..1023
    const int b    = wg >> 4;
    const int tile = wg & 15;
    const int l0   = tile * TM;
    const int tid  = threadIdx.x;
    const int lane = tid & 63, w = tid >> 6;   // w = 0..15

    __shared__ alignas(16) unsigned short Alds[4][TM * 64];  // 4 x 8 KB, XOR-swizzled bf16
    __shared__ float red[16][TM];              // per-wave row score partials
    __shared__ float plds[TM];                 // tile-local exp(s - m)
    char* const alds = (char*)Alds;

    f32x4 acc[4][2];
#pragma unroll
    for (int mi = 0; mi < 4; ++mi)
#pragma unroll
        for (int ni = 0; ni < 2; ++ni)
            acc[mi][ni] = (f32x4){0.f, 0.f, 0.f, 0.f};

    // staging: thread loads 4 fp32 (16B) of row (tid>>4), k-chunk (tid&15)*4
    const int srow  = tid >> 4;
    const int sbyte = srow * 128 + (((tid & 15) * 8) ^ ((srow & 7) << 4));
    char* const swp = alds + sbyte;
    const float* apt = enc + ((size_t)(b * Ln + l0 + srow)) * En + (tid & 15) * 4;

    // B fragments: f = (p*2+s)*32 + w*2 + ni ; addr = Wp + f*512 + lane*8
    const unsigned short* Bbase = Wp + (size_t)(w * 2) * 512 + lane * 8;

    // A fragments: row = mi*16 + (lane&15); k-byte = (s*64 + akb) ^ sw (full XOR)
    const int arow = lane & 15;
    const int akb  = (lane >> 4) * 16;
    const int sw   = (arow & 7) << 4;
    const char* const as0 = alds + arow * 128 + (akb ^ sw);
    const char* const as1 = alds + arow * 128 + ((64 + akb) ^ sw);

    // B register sets (double-buffered across phases)
    short8 fa00, fa01, fa10, fa11;   // even phases
    short8 fb00, fb01, fb10, fb11;   // odd phases

    // prologue: tiles 0,1 staged; ring ra,rb holds tiles 2,3; B for phase 0
    float4 ra = *(const float4*)(apt);
    float4 rb = *(const float4*)(apt + 64);
    STAGE(0, ra)
    STAGE(1, rb)
    ra = *(const float4*)(apt + 2 * 64);
    rb = *(const float4*)(apt + 3 * 64);
    BLOAD(fa, 0)

    for (int p = 0; p < 32; p += 4){
        __syncthreads();
        {   // phase p: issue B(p+1); stage tiles p+2,p+3 -> Q2,Q3; reload ring; MFMA Q0 w/ fa
            BLOAD(fb, p + 1)
            STAGE(2, ra)
            STAGE(3, rb)
            int t0 = p + 4 > 31 ? 31 : p + 4;   // clamped tail loads (unread)
            int t1 = p + 5 > 31 ? 31 : p + 5;
            ra = *(const float4*)(apt + t0 * 64);
            rb = *(const float4*)(apt + t1 * 64);
            MFMAS(0, fa)
        }
        {   // phase p+1: issue B(p+2); MFMA Q1 w/ fb
            BLOAD(fa, p + 2)
            MFMAS(1, fb)
        }
        __syncthreads();
        {   // phase p+2: issue B(p+3); stage tiles p+4,p+5 -> Q0,Q1; reload ring; MFMA Q2 w/ fa
            BLOAD(fb, p + 3)
            STAGE(0, ra)
            STAGE(1, rb)
            int t0 = p + 6 > 31 ? 31 : p + 6;
            int t1 = p + 7 > 31 ? 31 : p + 7;
            ra = *(const float4*)(apt + t0 * 64);
            rb = *(const float4*)(apt + t1 * 64);
            MFMAS(2, fa)
        }
        {   // phase p+3: issue B(p+4); MFMA Q3 w/ fb
            BLOAD(fa, p + 4)
            MFMAS(3, fb)
        }
    }

    // ---- epilogue ----
    float be[2], a2[2], wfv[2];
    const int cbase = w * 32 + (lane & 15);
#pragma unroll
    for (int ni = 0; ni < 2; ++ni){
        int c = cbase + ni * 16;
        be[ni]  = benc[c];
        a2[ni]  = att2[b * An + c];
        wfv[ni] = wfull[c];
    }

    float tsum[4][4];
#pragma unroll
    for (int mi = 0; mi < 4; ++mi)
#pragma unroll
        for (int j = 0; j < 4; ++j)
            tsum[mi][j] = 0.f;
#pragma unroll
    for (int mi = 0; mi < 4; ++mi)
#pragma unroll
        for (int ni = 0; ni < 2; ++ni)
#pragma unroll
            for (int j = 0; j < 4; ++j){
                float vv = acc[mi][ni][j] + be[ni];
                acc[mi][ni][j] = vv;
                tsum[mi][j] += tanh_fast(vv + a2[ni]) * wfv[ni];
            }

#pragma unroll
    for (int mi = 0; mi < 4; ++mi)
#pragma unroll
        for (int j = 0; j < 4; ++j){
            float t = tsum[mi][j];
            t += __shfl_xor(t, 1); t += __shfl_xor(t, 2);
            t += __shfl_xor(t, 4); t += __shfl_xor(t, 8);
            if ((lane & 15) == 0)
                red[w][mi * 16 + (lane >> 4) * 4 + j] = t;
        }
    __syncthreads();

    if (tid < 64){   // wave 0: combine 16 wave-partials, tile softmax stats
        float s = 0.f;
#pragma unroll
        for (int k = 0; k < 16; ++k)
            s += red[k][tid];
        out[ALPHA_OFF + b * Ln + l0 + tid] = s;   // raw score; finalized in k_final
        float m = s;
        m = fmaxf(m, __shfl_xor(m, 1));  m = fmaxf(m, __shfl_xor(m, 2));
        m = fmaxf(m, __shfl_xor(m, 4));  m = fmaxf(m, __shfl_xor(m, 8));
        m = fmaxf(m, __shfl_xor(m, 16)); m = fmaxf(m, __shfl_xor(m, 32));
        float pv = __expf(s - m);
        float sm = pv;
        sm += __shfl_xor(sm, 1);  sm += __shfl_xor(sm, 2);
        sm += __shfl_xor(sm, 4);  sm += __shfl_xor(sm, 8);
        sm += __shfl_xor(sm, 16); sm += __shfl_xor(sm, 32);
        plds[tid] = pv;
        if (tid == 0){ ms_ws[wg * 2] = m; ms_ws[wg * 2 + 1] = sm; }
    }
    __syncthreads();

    // partial awe for this wave's 32 cols (rows complete within the wave)
    float pp0 = 0.f, pp1 = 0.f;
#pragma unroll
    for (int mi = 0; mi < 4; ++mi)
#pragma unroll
        for (int j = 0; j < 4; ++j){
            float pr = plds[mi * 16 + (lane >> 4) * 4 + j];
            pp0 += pr * acc[mi][0][j];
            pp1 += pr * acc[mi][1][j];
        }
    pp0 += __shfl_xor(pp0, 16); pp0 += __shfl_xor(pp0, 32);
    pp1 += __shfl_xor(pp1, 16); pp1 += __shfl_xor(pp1, 32);
    if (lane < 16){
        pawe_ws[(size_t)wg * An + w * 32 + lane]      = pp0;
        pawe_ws[(size_t)wg * An + w * 32 + 16 + lane] = pp1;
    }
}

// ---------- kernel 2: combine tiles, finalize awe + alpha ----------
__global__ __launch_bounds__(256) void k_final(const float* __restrict__ pawe,
                                               const float* __restrict__ ms,
                                               float* __restrict__ out){
    int b = blockIdx.x, tid = threadIdx.x;
    __shared__ float scale[NTILES];
    __shared__ float sh[2];   // inv_total, global max
    if (tid < 64){
        int lane = tid;
        float m = -1e30f, su = 0.f;
        if (lane < NTILES){ m = ms[(b * NTILES + lane) * 2]; su = ms[(b * NTILES + lane) * 2 + 1]; }
        float mm = m;
        mm = fmaxf(mm, __shfl_xor(mm, 1)); mm = fmaxf(mm, __shfl_xor(mm, 2));
        mm = fmaxf(mm, __shfl_xor(mm, 4)); mm = fmaxf(mm, __shfl_xor(mm, 8));
        float sc = (lane < NTILES) ? su * __expf(m - mm) : 0.f;
        float tot = sc;
        tot += __shfl_xor(tot, 1); tot += __shfl_xor(tot, 2);
        tot += __shfl_xor(tot, 4); tot += __shfl_xor(tot, 8);
        if (lane < NTILES) scale[lane] = __expf(m - mm);
        if (lane == 0){ sh[0] = 1.0f / tot; sh[1] = mm; }
    }
    __syncthreads();
    float inv = sh[0], mm = sh[1];
    for (int a = tid; a < An; a += 256){
        float s = 0.f;
#pragma unroll
        for (int t = 0; t < NTILES; ++t)
            s += pawe[((size_t)(b * NTILES + t)) * An + a] * scale[t];
        out[AWE_OFF + b * An + a] = s * inv;
    }
    for (int l = tid; l < Ln; l += 256){
        float s = out[ALPHA_OFF + b * Ln + l];
        out[ALPHA_OFF + b * Ln + l] = __expf(s - mm) * inv;
    }
}

extern "C" void kernel_launch(void* const* d_in, const int* in_sizes, int n_in,
                              void* d_out, int out_size, void* d_ws, size_t ws_size,
                              hipStream_t stream){
    const float* enc   = (const float*)d_in[0];
    const float* dh    = (const float*)d_in[1];
    const float* Wenc  = (const float*)d_in[2];
    const float* benc  = (const float*)d_in[3];
    const float* Wdec  = (const float*)d_in[4];
    const float* bdec  = (const float*)d_in[5];
    const float* wfull = (const float*)d_in[6];
    // d_in[7] = b_full: softmax-invariant, unused.
    float* out = (float*)d_out;

    char* ws = (char*)d_ws;
    unsigned short* Wp = (unsigned short*)ws;                       // 2 MB packed W
    float* att2 = (float*)(ws + (2u << 20));                        // 128 KB
    float* pawe = (float*)(ws + (2u << 20) + (128u << 10));         // 2 MB
    float* msb  = (float*)(ws + (4u << 20) + (128u << 10));         // 8 KB

    k_prep<<<576, 256, 0, stream>>>(Wenc, Wp, dh, Wdec, bdec, att2);
    k_main<<<Bn * NTILES, 1024, 0, stream>>>(enc, Wp, benc, att2, wfull, out, pawe, msb);
    k_final<<<Bn, 256, 0, stream>>>(pawe, msb, out);
}